// Round 5
// baseline (265.632 us; speedup 1.0000x reference)
//
#include <hip/hip_runtime.h>
#include <hip/hip_fp16.h>

// Pentalinear 9^5 LUT interpolation, binned-LDS pipeline v6.
// x: (4,5,1024,1024) fp32 in [0,1); LUT: (5, 9^5) fp32; out: (4,5,1024,1024) fp32.
//
// R4 changes (k4 phase-serialization-bound: 34% HBM, 13% VALU, 45% occ):
//  - k4: persistent 2-tile pipeline. Grid 512 (one dispatch round, 2 blocks/CU).
//    Tile t+1's x-loads issued after tile t's histogram -> HBM latency hides
//    under scan+stage+flush; flush stores drain under next tile's compute.
//    __launch_bounds__(1024,8) pins VGPR<=64 so 2 blocks/CU survive.
//  - k4 flush: 2 threads per bin (half-run each) -> all 1024 threads active.

#define HW_    (1024 * 1024)
#define NPIX   (4 * HW_)                 // 1<<22
#define LUTC   59049
#define NBIN   512
#define CAP    8704                      // mean 8192 + 5.7 sigma
#define OVFCAP 65536
#define PXB    4096                      // pixels per k4 tile
#define NCELL2 (9 * 9 * 8 * 8 * 8)      // 41472 cells in R
#define OVF_IDX 1023                     // overflow counter slot in gcnt

#define R_BYTES   ((size_t)NCELL2 * 80)                       // 3,317,760
#define PAY_ENT   ((size_t)NBIN * CAP + OVFCAP)               // 4,521,984
#define PAY_BYTES (PAY_ENT * 16)                              // 72,351,744
#define POS_BYTES ((size_t)NPIX * 4)                          // 16,777,216
#define OFF_R    ((size_t)0)
#define OFF_PAY  (OFF_R + R_BYTES)
#define OFF_POS  (OFF_PAY + PAY_BYTES)
#define OFF_CNT  (OFF_POS + POS_BYTES)
#define CNT_BYTES ((size_t)4096)
#define WS_NEED  (OFF_CNT + CNT_BYTES)                        // 92,450,816

typedef _Float16 v2h __attribute__((ext_vector_type(2)));
typedef float    f4v __attribute__((ext_vector_type(4)));
union H2U { __half2 h; uint u; v2h v; };
union H8U { uint4 q; __half2 h2[4]; };
union HQ8 { __half h[8]; uint4 q; };

// ------------------------------------------------------------------ K1
// grid 648 = 81*8, bid = (i0*9+i1)*8 + i2.
__global__ __launch_bounds__(256) void k1_buildR(
    const float* __restrict__ lut, __half* __restrict__ R)
{
    __shared__ float s[5 * 162];
    int bid = blockIdx.x;
    int i2 = bid & 7;
    int r  = bid >> 3;               // i0*9+i1
    int Q  = r * 9 + i2;
    const int fb = Q * 81;
    for (int u = threadIdx.x; u < 5 * 162; u += 256) {
        int c = u / 162; int j = u - c * 162;
        s[u] = lut[(size_t)c * LUTC + fb + j];
    }
    __syncthreads();
    int cellBaseG = bid * 64;
    for (int t = threadIdx.x; t < 320; t += 256) {
        int cell = t / 5; int c = t - cell * 5;
        int i3 = cell >> 3, i4 = cell & 7;
        const float* L = s + c * 162 + i3 * 9 + i4;
        HQ8 u;
        // paired across b2: h[2j]=(b2=0), h[2j+1]=(b2=1) for (b3,b4)=j
        u.h[0] = __float2half(L[0]);   u.h[1] = __float2half(L[81]);   // b3b4=00
        u.h[2] = __float2half(L[1]);   u.h[3] = __float2half(L[82]);   // b3b4=01
        u.h[4] = __float2half(L[9]);   u.h[5] = __float2half(L[90]);   // b3b4=10
        u.h[6] = __float2half(L[10]);  u.h[7] = __float2half(L[91]);   // b3b4=11
        ((uint4*)R)[(size_t)(cellBaseG + cell) * 5 + c] = u.q;
    }
}

// ------------------------------------------------------------------ K4 fused
// Persistent: 512 blocks x 2 tiles, 1024 threads, 4 px/thread/tile.
__global__ __launch_bounds__(1024, 8) void k4_fused(
    const float* __restrict__ x,
    uint* __restrict__ gcnt,                 // bins at [bin*2], ovf at [1023]
    uint4* __restrict__ pay, uint* __restrict__ sortpos)
{
    __shared__ uint4  sPay[PXB];             // 64 KB
    __shared__ uint   sStart[NBIN];          // exclusive start within tile (2 KB)
    __shared__ uint   sCur[NBIN];            // hist -> rank cursor -> count (2 KB)
    __shared__ uint   sCB[NBIN];             // global chunk base (2 KB)
    __shared__ uint   sWsum[8];

    int tid = threadIdx.x;
    int tile0 = blockIdx.x * 2;

    f4v xv[2][5];
    {   // prologue: load tile0
        int pB = tile0 * PXB + tid * 4;
        int b = pB >> 20, hw = pB & (HW_ - 1);
        const float* xp = x + (size_t)b * 5 * HW_ + hw;
        #pragma unroll
        for (int d = 0; d < 5; ++d)
            xv[0][d] = __builtin_nontemporal_load((const f4v*)(xp + (size_t)d * HW_));
    }

    #pragma unroll
    for (int t = 0; t < 2; ++t) {
        int pBase = (tile0 + t) * PXB + tid * 4;

        __syncthreads();                     // prev flush done (LDS reuse guard)
        if (tid < NBIN) sCur[tid] = 0;
        __syncthreads();

        // ---- compute payloads from xv[t]; histogram into sCur
        uint4 plr[4]; uint keyr[4];
        #pragma unroll
        for (int j = 0; j < 4; ++j) {
            float f[5]; int idx[5];
            #pragma unroll
            for (int d = 0; d < 5; ++d) {
                float xs = xv[t][d][j] * 8.0f;
                int i = (int)floorf(xs); i = i < 0 ? 0 : (i > 7 ? 7 : i);
                idx[d] = i; f[d] = xs - (float)i;
            }
            int key   = (idx[0] << 6) | (idx[1] << 3) | idx[2];
            int local = (idx[3] << 3) | idx[4];
            H2U a, bq, c;
            a.h  = __float22half2_rn(make_float2(f[0], f[1]));
            bq.h = __float22half2_rn(make_float2(f[2], f[3]));
            c.h  = __float22half2_rn(make_float2(f[4], 0.f));
            plr[j].x = a.u; plr[j].y = bq.u; plr[j].z = c.u;
            plr[j].w = (uint)(pBase + j) | ((uint)local << 22);
            keyr[j] = (uint)key;
            atomicAdd(&sCur[keyr[j]], 1u);
        }

        // ---- prefetch next tile's x NOW; latency hides under scan+stage+flush
        if (t == 0) {
            int pB = (tile0 + 1) * PXB + tid * 4;
            int b = pB >> 20, hw = pB & (HW_ - 1);
            const float* xp = x + (size_t)b * 5 * HW_ + hw;
            #pragma unroll
            for (int d = 0; d < 5; ++d)
                xv[1][d] = __builtin_nontemporal_load((const f4v*)(xp + (size_t)d * HW_));
        }
        __syncthreads();

        // ---- scan 512 bins: per-wave shfl scan + cross-wave combine
        uint v = 0, s = 0, base = 0;
        if (tid < NBIN) {
            v = sCur[tid];
            // global chunk reservation issued NOW; latency hides under scan
            if (v) base = atomicAdd(&gcnt[tid * 2], v);
            s = v;
            #pragma unroll
            for (int off = 1; off < 64; off <<= 1) {
                uint tt = __shfl_up(s, off);
                if ((tid & 63) >= off) s += tt;
            }
            if ((tid & 63) == 63) sWsum[tid >> 6] = s;
        }
        __syncthreads();
        if (tid < NBIN) {
            uint add = 0;
            #pragma unroll
            for (int w = 0; w < 8; ++w)
                add += (w < (tid >> 6)) ? sWsum[w] : 0u;
            sStart[tid] = s + add - v;       // exclusive start within tile
            sCB[tid]    = base;
            sCur[tid]   = 0;                 // reset as rank cursor
        }
        __syncthreads();

        // ---- stage into bin-sorted LDS order; write sortpos (uint4)
        uint dstr[4];
        #pragma unroll
        for (int j = 0; j < 4; ++j) {
            uint key  = keyr[j];
            uint rank = atomicAdd(&sCur[key], 1u);
            uint slot = sStart[key] + rank;
            sPay[slot] = plr[j];
            uint gIdx = sCB[key] + rank;
            uint dst;
            if (gIdx < CAP) {
                dst = key * CAP + gIdx;
            } else {                          // overflow net (≈ never)
                uint oi = atomicAdd(&gcnt[OVF_IDX], 1u);
                if (oi >= OVFCAP) oi = OVFCAP - 1;
                pay[(size_t)NBIN * CAP + oi] = plr[j];
                dst = (uint)(NBIN * CAP) + oi;
            }
            dstr[j] = dst;
        }
        *(uint4*)(sortpos + pBase) = make_uint4(dstr[0], dstr[1], dstr[2], dstr[3]);
        __syncthreads();

        // ---- flush: 2 threads per bin, each streams half the bin's run
        {
            uint bin  = tid & (NBIN - 1);
            uint half = tid >> 9;
            uint cnt = sCur[bin];
            uint st  = sStart[bin];
            uint cb  = sCB[bin];
            uint j0  = (cnt * half) >> 1;
            uint j1  = (cnt * (half + 1)) >> 1;
            uint4* gp = pay + (size_t)bin * CAP;
            for (uint j = j0; j < j1; ++j) {
                uint gIdx = cb + j;
                if (gIdx < CAP)
                    gp[gIdx] = sPay[st + j];
            }
        }
        // loop-top barrier guards sPay/sCur reuse
    }
}

// ------------------------------------------------------------------ K5
// grid 2048: block handles quarter q of bin (bid>>2). Table 20.5 KB in LDS.
__global__ __launch_bounds__(256, 7) void k5_compute(
    const __half* __restrict__ R, const uint* __restrict__ gcnt,
    uint4* __restrict__ pay)
{
    __shared__ uint4 stbl[1280];     // 4 slabs * 64 cells * 5 ch
    int bid = blockIdx.x;
    int bin = bid >> 2, q = bid & 3;
    int i0 = bin >> 6, i1 = (bin >> 3) & 7, i2 = bin & 7;
    const uint4* R4 = (const uint4*)R;
    #pragma unroll
    for (int slab = 0; slab < 4; ++slab) {
        int a = slab >> 1, bcorner = slab & 1;
        size_t srcBase = (size_t)((((i0 + a) * 9 + (i1 + bcorner)) * 8 + i2) * 64) * 5;
        for (int rr = threadIdx.x; rr < 320; rr += 256)
            stbl[slab * 320 + rr] = R4[srcBase + rr];
    }
    __syncthreads();
    uint n = gcnt[bin * 2]; if (n > CAP) n = CAP;
    uint B0 = (uint)bin * CAP;
    uint st = B0 + ((n * q) >> 2), en = B0 + ((n * (q + 1)) >> 2);
    for (uint i = st + threadIdx.x; i < en; i += 256) {
        uint4 pl = pay[i];
        H2U f01, f23, f4x; f01.u = pl.x; f23.u = pl.y; f4x.u = pl.z;
        float2 F01 = __half22float2(f01.h);
        float2 F23 = __half22float2(f23.h);
        float f0 = F01.x, f1 = F01.y, f2 = F23.x;
        __half2 f33 = __half2half2(__high2half(f23.h));
        __half2 f44 = __half2half2(__low2half(f4x.h));
        int local = (int)(pl.w >> 22);
        const uint4* cbase = stbl + local * 5;
        float g0 = 1.f - f0, g1 = 1.f - f1, g2 = 1.f - f2;
        H2U wv[4];
        float w00 = g0 * g1, w01c = g0 * f1, w10 = f0 * g1, w11 = f0 * f1;
        wv[0].h = __float22half2_rn(make_float2(w00  * g2, w00  * f2));
        wv[1].h = __float22half2_rn(make_float2(w01c * g2, w01c * f2));
        wv[2].h = __float22half2_rn(make_float2(w10  * g2, w10  * f2));
        wv[3].h = __float22half2_rn(make_float2(w11  * g2, w11  * f2));
        float acc[5];
        #pragma unroll
        for (int c = 0; c < 5; ++c) acc[c] = 0.f;
        #pragma unroll
        for (int slab = 0; slab < 4; ++slab) {
            #pragma unroll
            for (int c = 0; c < 5; ++c) {
                H8U u; u.q = cbase[slab * 320 + c];
                __half2 e0 = __hfma2(f44, __hsub2(u.h2[1], u.h2[0]), u.h2[0]);
                __half2 e1 = __hfma2(f44, __hsub2(u.h2[3], u.h2[2]), u.h2[2]);
                H2U dd; dd.h = __hfma2(f33, __hsub2(e1, e0), e0);
#if __has_builtin(__builtin_amdgcn_fdot2)
                acc[c] = __builtin_amdgcn_fdot2(dd.v, wv[slab].v, acc[c], false);
#else
                float2 D = __half22float2(dd.h);
                float2 W = __half22float2(wv[slab].h);
                acc[c] = fmaf(D.x, W.x, fmaf(D.y, W.y, acc[c]));
#endif
            }
        }
        H2U o01, o23, o4x;
        o01.h = __float22half2_rn(make_float2(acc[0], acc[1]));
        o23.h = __float22half2_rn(make_float2(acc[2], acc[3]));
        o4x.h = __float22half2_rn(make_float2(acc[4], 0.f));
        uint4 res; res.x = o01.u; res.y = o23.u; res.z = o4x.u; res.w = pl.w;
        pay[i] = res;
    }
}

// ------------------------------------------------------------------ K5ovf
// Processes overflow payloads with a direct global gather (correctness net).
__global__ __launch_bounds__(256) void k5_ovf(
    const float* __restrict__ x, const __half* __restrict__ R,
    const uint* __restrict__ gcnt, uint4* __restrict__ pay)
{
    uint n = gcnt[OVF_IDX]; if (n > OVFCAP) n = OVFCAP;
    for (uint i = blockIdx.x * 256 + threadIdx.x; i < n; i += 64 * 256) {
        uint4 pl = pay[(size_t)NBIN * CAP + i];
        uint p = pl.w & 0x3FFFFFu;
        int b = p >> 20, hw = p & (HW_ - 1);
        const float* xp = x + (size_t)b * 5 * HW_ + hw;
        float f[5]; int idx[5];
        #pragma unroll
        for (int d = 0; d < 5; ++d) {
            float xs = xp[(size_t)d * HW_] * 8.0f;
            int ii = (int)floorf(xs); ii = ii < 0 ? 0 : (ii > 7 ? 7 : ii);
            idx[d] = ii; f[d] = xs - (float)ii;
        }
        float g0 = 1.f - f[0], g1 = 1.f - f[1];
        float f2 = f[2], f3 = f[3], f4 = f[4];
        int cellBase = ((idx[0] * 9 + idx[1]) * 8 + idx[2]) * 64 + idx[3] * 8 + idx[4];
        float acc[5];
        #pragma unroll
        for (int c = 0; c < 5; ++c) acc[c] = 0.f;
        #pragma unroll
        for (int c0 = 0; c0 < 2; ++c0) {
            float w0 = c0 ? f[0] : g0;
            int o0 = cellBase + c0 * 4608;            // +9*8*64 cells
            #pragma unroll
            for (int c1 = 0; c1 < 2; ++c1) {
                float w = w0 * (c1 ? f[1] : g1);
                const uint4* pc = (const uint4*)R + (size_t)(o0 + c1 * 512) * 5;
                #pragma unroll
                for (int c = 0; c < 5; ++c) {
                    HQ8 u; u.q = pc[c];
                    // h[2j]=(b2=0), h[2j+1]=(b2=1), j=(b3,b4)
                    float e00 = __half2float(u.h[0]) + f2 * (__half2float(u.h[1]) - __half2float(u.h[0]));
                    float e01 = __half2float(u.h[2]) + f2 * (__half2float(u.h[3]) - __half2float(u.h[2]));
                    float e10 = __half2float(u.h[4]) + f2 * (__half2float(u.h[5]) - __half2float(u.h[4]));
                    float e11 = __half2float(u.h[6]) + f2 * (__half2float(u.h[7]) - __half2float(u.h[6]));
                    float d0 = e00 + f4 * (e01 - e00);
                    float d1 = e10 + f4 * (e11 - e10);
                    float vv = d0 + f3 * (d1 - d0);
                    acc[c] = fmaf(w, vv, acc[c]);
                }
            }
        }
        H2U o01, o23, o4x;
        o01.h = __float22half2_rn(make_float2(acc[0], acc[1]));
        o23.h = __float22half2_rn(make_float2(acc[2], acc[3]));
        o4x.h = __float22half2_rn(make_float2(acc[4], 0.f));
        uint4 res; res.x = o01.u; res.y = o23.u; res.z = o4x.u; res.w = pl.w;
        pay[(size_t)NBIN * CAP + i] = res;
    }
}

// ------------------------------------------------------------------ K6
// grid 1024: block span = 4096 px = one k4 tile's span, so each pay line's
// 4 entries (consecutive ranks of one bin run) are consumed block-locally.
__global__ __launch_bounds__(1024) void k6_unpermute(
    const uint* __restrict__ sortpos, const uint4* __restrict__ res,
    float* __restrict__ out)
{
    int pBase = blockIdx.x * 4096 + threadIdx.x * 4;
    uint4 d4 = *(const uint4*)(sortpos + pBase);
    uint4 r0 = res[d4.x];
    uint4 r1 = res[d4.y];
    uint4 r2 = res[d4.z];
    uint4 r3 = res[d4.w];
    H2U a0, a1, a2, a3, b0, b1, b2, b3, c0, c1, c2, c3;
    a0.u = r0.x; b0.u = r0.y; c0.u = r0.z;
    a1.u = r1.x; b1.u = r1.y; c1.u = r1.z;
    a2.u = r2.x; b2.u = r2.y; c2.u = r2.z;
    a3.u = r3.x; b3.u = r3.y; c3.u = r3.z;
    float2 A0 = __half22float2(a0.h), A1 = __half22float2(a1.h);
    float2 A2 = __half22float2(a2.h), A3 = __half22float2(a3.h);
    float2 B0 = __half22float2(b0.h), B1 = __half22float2(b1.h);
    float2 B2 = __half22float2(b2.h), B3 = __half22float2(b3.h);
    float2 C0 = __half22float2(c0.h), C1 = __half22float2(c1.h);
    float2 C2 = __half22float2(c2.h), C3 = __half22float2(c3.h);
    int b = pBase >> 20, hw = pBase & (HW_ - 1);
    float* op = out + (size_t)b * 5 * HW_ + hw;
    f4v o;
    o[0] = A0.x; o[1] = A1.x; o[2] = A2.x; o[3] = A3.x;
    __builtin_nontemporal_store(o, (f4v*)(op));
    o[0] = A0.y; o[1] = A1.y; o[2] = A2.y; o[3] = A3.y;
    __builtin_nontemporal_store(o, (f4v*)(op + HW_));
    o[0] = B0.x; o[1] = B1.x; o[2] = B2.x; o[3] = B3.x;
    __builtin_nontemporal_store(o, (f4v*)(op + 2 * HW_));
    o[0] = B0.y; o[1] = B1.y; o[2] = B2.y; o[3] = B3.y;
    __builtin_nontemporal_store(o, (f4v*)(op + 3 * HW_));
    o[0] = C0.x; o[1] = C1.x; o[2] = C2.x; o[3] = C3.x;
    __builtin_nontemporal_store(o, (f4v*)(op + 4 * HW_));
}

// ================= fallback: round-3 path (global gather, ~363 us) ==========
__global__ __launch_bounds__(256) void buildR3(
    const float* __restrict__ lut, __half* __restrict__ R)
{
    int t = blockIdx.x * blockDim.x + threadIdx.x;
    if (t >= 5 * NCELL2) return;
    int cell = t / 5;
    int c    = t - cell * 5;
    int i4 = cell & 7;
    int i3 = (cell >> 3) & 7;
    int i2 = (cell >> 6) & 7;
    int r  = cell >> 9;
    int i1 = r % 9;
    int i0 = r / 9;
    int flat = (((i0 * 9 + i1) * 9 + i2) * 9 + i3) * 9 + i4;
    const float* qq = lut + c * LUTC + flat;
    HQ8 u;
    u.h[0] = __float2half(qq[0]);  u.h[1] = __float2half(qq[1]);
    u.h[2] = __float2half(qq[9]);  u.h[3] = __float2half(qq[10]);
    u.h[4] = __float2half(qq[81]); u.h[5] = __float2half(qq[82]);
    u.h[6] = __float2half(qq[90]); u.h[7] = __float2half(qq[91]);
    ((uint4*)R)[t] = u.q;
}

__device__ __forceinline__ float lerpf(float a, float b, float t) {
    return fmaf(t, b - a, a);
}

__global__ __launch_bounds__(256) void gather3(
    const float* __restrict__ x, const __half* __restrict__ R,
    float* __restrict__ out)
{
    int p = blockIdx.x * blockDim.x + threadIdx.x;
    if (p >= NPIX) return;
    int b  = p >> 20;
    int hw = p & (HW_ - 1);
    const float* xp = x + (size_t)b * 5 * HW_ + hw;
    float f[5], g[5]; int idx[5];
    #pragma unroll
    for (int d = 0; d < 5; ++d) {
        float xs = __builtin_nontemporal_load(xp + (size_t)d * HW_) * 8.0f;
        int i = (int)floorf(xs); i = i < 0 ? 0 : (i > 7 ? 7 : i);
        idx[d] = i; f[d] = xs - (float)i; g[d] = 1.0f - f[d];
    }
    const float f2 = f[2], f3 = f[3], f4 = f[4];
    int base = ((idx[0] * 9 + idx[1]) * 8 + idx[2]) * 64 + idx[3] * 8 + idx[4];
    float acc0 = 0.f, acc1 = 0.f, acc2 = 0.f, acc3 = 0.f, acc4 = 0.f;
    #pragma unroll
    for (int c0 = 0; c0 < 2; ++c0) {
        const float w0 = c0 ? f[0] : g[0];
        const int  o0  = base + c0 * 4608;
        #pragma unroll
        for (int c1 = 0; c1 < 2; ++c1) {
            const float w  = w0 * (c1 ? f[1] : g[1]);
            const __half* pc = R + (size_t)(o0 + c1 * 512) * 40;
            #pragma unroll
            for (int c = 0; c < 5; ++c) {
                HQ8 u; u.q = *(const uint4*)(pc + c * 8);
                float v000 = __half2float(u.h[0]);
                float v001 = __half2float(u.h[1]);
                float v010 = __half2float(u.h[2]);
                float v011 = __half2float(u.h[3]);
                float v100 = __half2float(u.h[4]);
                float v101 = __half2float(u.h[5]);
                float v110 = __half2float(u.h[6]);
                float v111 = __half2float(u.h[7]);
                float e00 = lerpf(v000, v001, f2);
                float e01 = lerpf(v010, v011, f2);
                float e10 = lerpf(v100, v101, f2);
                float e11 = lerpf(v110, v111, f2);
                float d0  = lerpf(e00, e01, f4);
                float d1  = lerpf(e10, e11, f4);
                float s   = lerpf(d0, d1, f3);
                if      (c == 0) acc0 = fmaf(w, s, acc0);
                else if (c == 1) acc1 = fmaf(w, s, acc1);
                else if (c == 2) acc2 = fmaf(w, s, acc2);
                else if (c == 3) acc3 = fmaf(w, s, acc3);
                else             acc4 = fmaf(w, s, acc4);
            }
        }
    }
    float* op = out + (size_t)b * 5 * HW_ + hw;
    __builtin_nontemporal_store(acc0, op + 0 * HW_);
    __builtin_nontemporal_store(acc1, op + 1 * HW_);
    __builtin_nontemporal_store(acc2, op + 2 * HW_);
    __builtin_nontemporal_store(acc3, op + 3 * HW_);
    __builtin_nontemporal_store(acc4, op + 4 * HW_);
}

extern "C" void kernel_launch(void* const* d_in, const int* in_sizes, int n_in,
                              void* d_out, int out_size, void* d_ws, size_t ws_size,
                              hipStream_t stream)
{
    const float* x   = (const float*)d_in[0];
    const float* lut = (const float*)d_in[1];
    float* out       = (float*)d_out;
    char* ws         = (char*)d_ws;

    if (ws != nullptr && ws_size >= WS_NEED) {
        __half* R      = (__half*)(ws + OFF_R);
        uint4*  pay    = (uint4*)(ws + OFF_PAY);
        uint*   sortp  = (uint*)(ws + OFF_POS);
        uint*   gcnt   = (uint*)(ws + OFF_CNT);

        hipMemsetAsync(gcnt, 0, CNT_BYTES, stream);
        k1_buildR   <<<648, 256, 0, stream>>>(lut, R);
        k4_fused    <<<NPIX / PXB / 2, 1024, 0, stream>>>(x, gcnt, pay, sortp);
        k5_compute  <<<4 * NBIN, 256, 0, stream>>>(R, gcnt, pay);
        k5_ovf      <<<64, 256, 0, stream>>>(x, R, gcnt, pay);
        k6_unpermute<<<NPIX / 4096, 1024, 0, stream>>>(sortp, pay, out);
    } else if (ws != nullptr && ws_size >= R_BYTES) {
        // note: buildR3 uses the round-3 corner layout; gather3 lerps match it
        __half* R = (__half*)ws;
        int nb = (5 * NCELL2 + 255) / 256;
        buildR3<<<nb, 256, 0, stream>>>(lut, R);
        gather3<<<NPIX / 256, 256, 0, stream>>>(x, R, out);
    }
}

// Round 6
// 239.444 us; speedup vs baseline: 1.1094x; 1.1094x over previous
//
#include <hip/hip_runtime.h>
#include <hip/hip_fp16.h>

// Pentalinear 9^5 LUT interpolation, binned-LDS pipeline v7.
// x: (4,5,1024,1024) fp32 in [0,1); LUT: (5, 9^5) fp32; out: (4,5,1024,1024) fp32.
//
// R5: revert R4's persistent pipeline (it broke store coalescing: WRITE 104->165,
// RFO FETCH +26 MB). Back to R3 structure; ONE change: wave-cooperative flush.
// 8-lane group per bin -> each store instr writes 8 x ~128 B contiguous runs
// (full 64 B lines) instead of 64 x 16 B scattered partial lines.

#define HW_    (1024 * 1024)
#define NPIX   (4 * HW_)                 // 1<<22
#define LUTC   59049
#define NBIN   512
#define CAP    8704                      // mean 8192 + 5.7 sigma
#define OVFCAP 65536
#define PXB    4096                      // pixels per k4 block
#define NCELL2 (9 * 9 * 8 * 8 * 8)      // 41472 cells in R
#define OVF_IDX 1023                     // overflow counter slot in gcnt

#define R_BYTES   ((size_t)NCELL2 * 80)                       // 3,317,760
#define PAY_ENT   ((size_t)NBIN * CAP + OVFCAP)               // 4,521,984
#define PAY_BYTES (PAY_ENT * 16)                              // 72,351,744
#define POS_BYTES ((size_t)NPIX * 4)                          // 16,777,216
#define OFF_R    ((size_t)0)
#define OFF_PAY  (OFF_R + R_BYTES)
#define OFF_POS  (OFF_PAY + PAY_BYTES)
#define OFF_CNT  (OFF_POS + POS_BYTES)
#define CNT_BYTES ((size_t)4096)
#define WS_NEED  (OFF_CNT + CNT_BYTES)                        // 92,450,816

typedef _Float16 v2h __attribute__((ext_vector_type(2)));
typedef float    f4v __attribute__((ext_vector_type(4)));
union H2U { __half2 h; uint u; v2h v; };
union H8U { uint4 q; __half2 h2[4]; };
union HQ8 { __half h[8]; uint4 q; };

// ------------------------------------------------------------------ K1
// grid 648 = 81*8, bid = (i0*9+i1)*8 + i2.
__global__ __launch_bounds__(256) void k1_buildR(
    const float* __restrict__ lut, __half* __restrict__ R)
{
    __shared__ float s[5 * 162];
    int bid = blockIdx.x;
    int i2 = bid & 7;
    int r  = bid >> 3;               // i0*9+i1
    int Q  = r * 9 + i2;
    const int fb = Q * 81;
    for (int u = threadIdx.x; u < 5 * 162; u += 256) {
        int c = u / 162; int j = u - c * 162;
        s[u] = lut[(size_t)c * LUTC + fb + j];
    }
    __syncthreads();
    int cellBaseG = bid * 64;
    for (int t = threadIdx.x; t < 320; t += 256) {
        int cell = t / 5; int c = t - cell * 5;
        int i3 = cell >> 3, i4 = cell & 7;
        const float* L = s + c * 162 + i3 * 9 + i4;
        HQ8 u;
        // paired across b2: h[2j]=(b2=0), h[2j+1]=(b2=1) for (b3,b4)=j
        u.h[0] = __float2half(L[0]);   u.h[1] = __float2half(L[81]);   // b3b4=00
        u.h[2] = __float2half(L[1]);   u.h[3] = __float2half(L[82]);   // b3b4=01
        u.h[4] = __float2half(L[9]);   u.h[5] = __float2half(L[90]);   // b3b4=10
        u.h[6] = __float2half(L[10]);  u.h[7] = __float2half(L[91]);   // b3b4=11
        ((uint4*)R)[(size_t)(cellBaseG + cell) * 5 + c] = u.q;
    }
}

// ------------------------------------------------------------------ K4 fused
// 1024 threads, 4 consecutive pixels per thread, PXB=4096.
__global__ __launch_bounds__(1024) void k4_fused(
    const float* __restrict__ x,
    uint* __restrict__ gcnt,                 // bins at [bin*2], ovf at [1023]
    uint4* __restrict__ pay, uint* __restrict__ sortpos)
{
    __shared__ uint4  sPay[PXB];             // 64 KB
    __shared__ uint   sStart[NBIN];          // exclusive start within block (2 KB)
    __shared__ uint   sCur[NBIN];            // hist -> rank cursor -> count (2 KB)
    __shared__ uint   sCB[NBIN];             // global chunk base (2 KB)
    __shared__ uint   sWsum[8];

    int tid = threadIdx.x, blk = blockIdx.x;
    if (tid < NBIN) sCur[tid] = 0;
    __syncthreads();

    // ---- load 4 consecutive pixels per thread; histogram into sCur
    int pBase = blk * PXB + tid * 4;
    int b = pBase >> 20, hw = pBase & (HW_ - 1);
    const float* xp = x + (size_t)b * 5 * HW_ + hw;
    f4v xv[5];
    #pragma unroll
    for (int d = 0; d < 5; ++d)
        xv[d] = __builtin_nontemporal_load((const f4v*)(xp + (size_t)d * HW_));

    uint4 plr[4]; uint keyr[4];
    #pragma unroll
    for (int j = 0; j < 4; ++j) {
        float f[5]; int idx[5];
        #pragma unroll
        for (int d = 0; d < 5; ++d) {
            float xs = xv[d][j] * 8.0f;
            int i = (int)floorf(xs); i = i < 0 ? 0 : (i > 7 ? 7 : i);
            idx[d] = i; f[d] = xs - (float)i;
        }
        int key   = (idx[0] << 6) | (idx[1] << 3) | idx[2];
        int local = (idx[3] << 3) | idx[4];
        H2U a, bq, c;
        a.h  = __float22half2_rn(make_float2(f[0], f[1]));
        bq.h = __float22half2_rn(make_float2(f[2], f[3]));
        c.h  = __float22half2_rn(make_float2(f[4], 0.f));
        plr[j].x = a.u; plr[j].y = bq.u; plr[j].z = c.u;
        plr[j].w = (uint)(pBase + j) | ((uint)local << 22);
        keyr[j] = (uint)key;
        atomicAdd(&sCur[key], 1u);
    }
    __syncthreads();

    // ---- scan 512 bins: per-wave shfl scan + cross-wave combine (1 barrier)
    uint v = 0, s = 0, base = 0;
    if (tid < NBIN) {
        v = sCur[tid];
        // global chunk reservation issued NOW; latency hides under scan
        if (v) base = atomicAdd(&gcnt[tid * 2], v);
        s = v;
        #pragma unroll
        for (int off = 1; off < 64; off <<= 1) {
            uint t = __shfl_up(s, off);
            if ((tid & 63) >= off) s += t;
        }
        if ((tid & 63) == 63) sWsum[tid >> 6] = s;
    }
    __syncthreads();
    if (tid < NBIN) {
        uint add = 0;
        #pragma unroll
        for (int w = 0; w < 8; ++w)
            add += (w < (tid >> 6)) ? sWsum[w] : 0u;
        sStart[tid] = s + add - v;           // exclusive start within block
        sCB[tid]    = base;
        sCur[tid]   = 0;                     // reset as rank cursor
    }
    __syncthreads();

    // ---- stage into bin-sorted LDS order; write sortpos (uint4, plain -> L3)
    uint dstr[4];
    #pragma unroll
    for (int j = 0; j < 4; ++j) {
        uint key  = keyr[j];
        uint rank = atomicAdd(&sCur[key], 1u);
        uint slot = sStart[key] + rank;
        sPay[slot] = plr[j];
        uint gIdx = sCB[key] + rank;
        uint dst;
        if (gIdx < CAP) {
            dst = key * CAP + gIdx;
        } else {                              // overflow net (≈ never)
            uint oi = atomicAdd(&gcnt[OVF_IDX], 1u);
            if (oi >= OVFCAP) oi = OVFCAP - 1;
            pay[(size_t)NBIN * CAP + oi] = plr[j];
            dst = (uint)(NBIN * CAP) + oi;
        }
        dstr[j] = dst;
    }
    *(uint4*)(sortpos + pBase) = make_uint4(dstr[0], dstr[1], dstr[2], dstr[3]);
    __syncthreads();

    // ---- flush: wave-cooperative. 8-lane group per bin: lanes write the
    // bin's run as contiguous 16 B entries -> each store instruction covers
    // 8 runs x 128 B contiguous (full 64 B lines) instead of 64 scattered 16 B.
    {
        int wave = tid >> 6, lane = tid & 63;
        uint wbase = (uint)wave * 32;            // 16 waves * 32 bins = 512
        #pragma unroll
        for (int g = 0; g < 4; ++g) {
            uint bin = wbase + g * 8 + (lane >> 3);
            uint cnt = sCur[bin];
            uint st  = sStart[bin];
            uint cb  = sCB[bin];
            uint4* gp = pay + (size_t)bin * CAP;
            for (uint e = (uint)(lane & 7); e < cnt; e += 8) {
                uint gIdx = cb + e;
                if (gIdx < CAP)
                    gp[gIdx] = sPay[st + e];
            }
        }
    }
}

// ------------------------------------------------------------------ K5
// grid 2048: block handles quarter q of bin (bid>>2). Table 20.5 KB in LDS.
__global__ __launch_bounds__(256, 7) void k5_compute(
    const __half* __restrict__ R, const uint* __restrict__ gcnt,
    uint4* __restrict__ pay)
{
    __shared__ uint4 stbl[1280];     // 4 slabs * 64 cells * 5 ch
    int bid = blockIdx.x;
    int bin = bid >> 2, q = bid & 3;
    int i0 = bin >> 6, i1 = (bin >> 3) & 7, i2 = bin & 7;
    const uint4* R4 = (const uint4*)R;
    #pragma unroll
    for (int slab = 0; slab < 4; ++slab) {
        int a = slab >> 1, bcorner = slab & 1;
        size_t srcBase = (size_t)((((i0 + a) * 9 + (i1 + bcorner)) * 8 + i2) * 64) * 5;
        for (int rr = threadIdx.x; rr < 320; rr += 256)
            stbl[slab * 320 + rr] = R4[srcBase + rr];
    }
    __syncthreads();
    uint n = gcnt[bin * 2]; if (n > CAP) n = CAP;
    uint B0 = (uint)bin * CAP;
    uint st = B0 + ((n * q) >> 2), en = B0 + ((n * (q + 1)) >> 2);
    for (uint i = st + threadIdx.x; i < en; i += 256) {
        uint4 pl = pay[i];
        H2U f01, f23, f4x; f01.u = pl.x; f23.u = pl.y; f4x.u = pl.z;
        float2 F01 = __half22float2(f01.h);
        float2 F23 = __half22float2(f23.h);
        float f0 = F01.x, f1 = F01.y, f2 = F23.x;
        __half2 f33 = __half2half2(__high2half(f23.h));
        __half2 f44 = __half2half2(__low2half(f4x.h));
        int local = (int)(pl.w >> 22);
        const uint4* cbase = stbl + local * 5;
        float g0 = 1.f - f0, g1 = 1.f - f1, g2 = 1.f - f2;
        H2U wv[4];
        float w00 = g0 * g1, w01c = g0 * f1, w10 = f0 * g1, w11 = f0 * f1;
        wv[0].h = __float22half2_rn(make_float2(w00  * g2, w00  * f2));
        wv[1].h = __float22half2_rn(make_float2(w01c * g2, w01c * f2));
        wv[2].h = __float22half2_rn(make_float2(w10  * g2, w10  * f2));
        wv[3].h = __float22half2_rn(make_float2(w11  * g2, w11  * f2));
        float acc[5];
        #pragma unroll
        for (int c = 0; c < 5; ++c) acc[c] = 0.f;
        #pragma unroll
        for (int slab = 0; slab < 4; ++slab) {
            #pragma unroll
            for (int c = 0; c < 5; ++c) {
                H8U u; u.q = cbase[slab * 320 + c];
                __half2 e0 = __hfma2(f44, __hsub2(u.h2[1], u.h2[0]), u.h2[0]);
                __half2 e1 = __hfma2(f44, __hsub2(u.h2[3], u.h2[2]), u.h2[2]);
                H2U dd; dd.h = __hfma2(f33, __hsub2(e1, e0), e0);
#if __has_builtin(__builtin_amdgcn_fdot2)
                acc[c] = __builtin_amdgcn_fdot2(dd.v, wv[slab].v, acc[c], false);
#else
                float2 D = __half22float2(dd.h);
                float2 W = __half22float2(wv[slab].h);
                acc[c] = fmaf(D.x, W.x, fmaf(D.y, W.y, acc[c]));
#endif
            }
        }
        H2U o01, o23, o4x;
        o01.h = __float22half2_rn(make_float2(acc[0], acc[1]));
        o23.h = __float22half2_rn(make_float2(acc[2], acc[3]));
        o4x.h = __float22half2_rn(make_float2(acc[4], 0.f));
        uint4 res; res.x = o01.u; res.y = o23.u; res.z = o4x.u; res.w = pl.w;
        pay[i] = res;
    }
}

// ------------------------------------------------------------------ K5ovf
// Processes overflow payloads with a direct global gather (correctness net).
__global__ __launch_bounds__(256) void k5_ovf(
    const float* __restrict__ x, const __half* __restrict__ R,
    const uint* __restrict__ gcnt, uint4* __restrict__ pay)
{
    uint n = gcnt[OVF_IDX]; if (n > OVFCAP) n = OVFCAP;
    for (uint i = blockIdx.x * 256 + threadIdx.x; i < n; i += 64 * 256) {
        uint4 pl = pay[(size_t)NBIN * CAP + i];
        uint p = pl.w & 0x3FFFFFu;
        int b = p >> 20, hw = p & (HW_ - 1);
        const float* xp = x + (size_t)b * 5 * HW_ + hw;
        float f[5]; int idx[5];
        #pragma unroll
        for (int d = 0; d < 5; ++d) {
            float xs = xp[(size_t)d * HW_] * 8.0f;
            int ii = (int)floorf(xs); ii = ii < 0 ? 0 : (ii > 7 ? 7 : ii);
            idx[d] = ii; f[d] = xs - (float)ii;
        }
        float g0 = 1.f - f[0], g1 = 1.f - f[1];
        float f2 = f[2], f3 = f[3], f4 = f[4];
        int cellBase = ((idx[0] * 9 + idx[1]) * 8 + idx[2]) * 64 + idx[3] * 8 + idx[4];
        float acc[5];
        #pragma unroll
        for (int c = 0; c < 5; ++c) acc[c] = 0.f;
        #pragma unroll
        for (int c0 = 0; c0 < 2; ++c0) {
            float w0 = c0 ? f[0] : g0;
            int o0 = cellBase + c0 * 4608;            // +9*8*64 cells
            #pragma unroll
            for (int c1 = 0; c1 < 2; ++c1) {
                float w = w0 * (c1 ? f[1] : g1);
                const uint4* pc = (const uint4*)R + (size_t)(o0 + c1 * 512) * 5;
                #pragma unroll
                for (int c = 0; c < 5; ++c) {
                    HQ8 u; u.q = pc[c];
                    // h[2j]=(b2=0), h[2j+1]=(b2=1), j=(b3,b4)
                    float e00 = __half2float(u.h[0]) + f2 * (__half2float(u.h[1]) - __half2float(u.h[0]));
                    float e01 = __half2float(u.h[2]) + f2 * (__half2float(u.h[3]) - __half2float(u.h[2]));
                    float e10 = __half2float(u.h[4]) + f2 * (__half2float(u.h[5]) - __half2float(u.h[4]));
                    float e11 = __half2float(u.h[6]) + f2 * (__half2float(u.h[7]) - __half2float(u.h[6]));
                    float d0 = e00 + f4 * (e01 - e00);
                    float d1 = e10 + f4 * (e11 - e10);
                    float vv = d0 + f3 * (d1 - d0);
                    acc[c] = fmaf(w, vv, acc[c]);
                }
            }
        }
        H2U o01, o23, o4x;
        o01.h = __float22half2_rn(make_float2(acc[0], acc[1]));
        o23.h = __float22half2_rn(make_float2(acc[2], acc[3]));
        o4x.h = __float22half2_rn(make_float2(acc[4], 0.f));
        uint4 res; res.x = o01.u; res.y = o23.u; res.z = o4x.u; res.w = pl.w;
        pay[(size_t)NBIN * CAP + i] = res;
    }
}

// ------------------------------------------------------------------ K6
// grid 1024: block span = 4096 px = one k4 block's span, so each pay line's
// 4 entries (consecutive ranks of one bin run) are consumed block-locally.
__global__ __launch_bounds__(1024) void k6_unpermute(
    const uint* __restrict__ sortpos, const uint4* __restrict__ res,
    float* __restrict__ out)
{
    int pBase = blockIdx.x * 4096 + threadIdx.x * 4;
    uint4 d4 = *(const uint4*)(sortpos + pBase);
    uint4 r0 = res[d4.x];
    uint4 r1 = res[d4.y];
    uint4 r2 = res[d4.z];
    uint4 r3 = res[d4.w];
    H2U a0, a1, a2, a3, b0, b1, b2, b3, c0, c1, c2, c3;
    a0.u = r0.x; b0.u = r0.y; c0.u = r0.z;
    a1.u = r1.x; b1.u = r1.y; c1.u = r1.z;
    a2.u = r2.x; b2.u = r2.y; c2.u = r2.z;
    a3.u = r3.x; b3.u = r3.y; c3.u = r3.z;
    float2 A0 = __half22float2(a0.h), A1 = __half22float2(a1.h);
    float2 A2 = __half22float2(a2.h), A3 = __half22float2(a3.h);
    float2 B0 = __half22float2(b0.h), B1 = __half22float2(b1.h);
    float2 B2 = __half22float2(b2.h), B3 = __half22float2(b3.h);
    float2 C0 = __half22float2(c0.h), C1 = __half22float2(c1.h);
    float2 C2 = __half22float2(c2.h), C3 = __half22float2(c3.h);
    int b = pBase >> 20, hw = pBase & (HW_ - 1);
    float* op = out + (size_t)b * 5 * HW_ + hw;
    f4v o;
    o[0] = A0.x; o[1] = A1.x; o[2] = A2.x; o[3] = A3.x;
    __builtin_nontemporal_store(o, (f4v*)(op));
    o[0] = A0.y; o[1] = A1.y; o[2] = A2.y; o[3] = A3.y;
    __builtin_nontemporal_store(o, (f4v*)(op + HW_));
    o[0] = B0.x; o[1] = B1.x; o[2] = B2.x; o[3] = B3.x;
    __builtin_nontemporal_store(o, (f4v*)(op + 2 * HW_));
    o[0] = B0.y; o[1] = B1.y; o[2] = B2.y; o[3] = B3.y;
    __builtin_nontemporal_store(o, (f4v*)(op + 3 * HW_));
    o[0] = C0.x; o[1] = C1.x; o[2] = C2.x; o[3] = C3.x;
    __builtin_nontemporal_store(o, (f4v*)(op + 4 * HW_));
}

// ================= fallback: round-3 path (global gather, ~363 us) ==========
__global__ __launch_bounds__(256) void buildR3(
    const float* __restrict__ lut, __half* __restrict__ R)
{
    int t = blockIdx.x * blockDim.x + threadIdx.x;
    if (t >= 5 * NCELL2) return;
    int cell = t / 5;
    int c    = t - cell * 5;
    int i4 = cell & 7;
    int i3 = (cell >> 3) & 7;
    int i2 = (cell >> 6) & 7;
    int r  = cell >> 9;
    int i1 = r % 9;
    int i0 = r / 9;
    int flat = (((i0 * 9 + i1) * 9 + i2) * 9 + i3) * 9 + i4;
    const float* qq = lut + c * LUTC + flat;
    HQ8 u;
    u.h[0] = __float2half(qq[0]);  u.h[1] = __float2half(qq[1]);
    u.h[2] = __float2half(qq[9]);  u.h[3] = __float2half(qq[10]);
    u.h[4] = __float2half(qq[81]); u.h[5] = __float2half(qq[82]);
    u.h[6] = __float2half(qq[90]); u.h[7] = __float2half(qq[91]);
    ((uint4*)R)[t] = u.q;
}

__device__ __forceinline__ float lerpf(float a, float b, float t) {
    return fmaf(t, b - a, a);
}

__global__ __launch_bounds__(256) void gather3(
    const float* __restrict__ x, const __half* __restrict__ R,
    float* __restrict__ out)
{
    int p = blockIdx.x * blockDim.x + threadIdx.x;
    if (p >= NPIX) return;
    int b  = p >> 20;
    int hw = p & (HW_ - 1);
    const float* xp = x + (size_t)b * 5 * HW_ + hw;
    float f[5], g[5]; int idx[5];
    #pragma unroll
    for (int d = 0; d < 5; ++d) {
        float xs = __builtin_nontemporal_load(xp + (size_t)d * HW_) * 8.0f;
        int i = (int)floorf(xs); i = i < 0 ? 0 : (i > 7 ? 7 : i);
        idx[d] = i; f[d] = xs - (float)i; g[d] = 1.0f - f[d];
    }
    const float f2 = f[2], f3 = f[3], f4 = f[4];
    int base = ((idx[0] * 9 + idx[1]) * 8 + idx[2]) * 64 + idx[3] * 8 + idx[4];
    float acc0 = 0.f, acc1 = 0.f, acc2 = 0.f, acc3 = 0.f, acc4 = 0.f;
    #pragma unroll
    for (int c0 = 0; c0 < 2; ++c0) {
        const float w0 = c0 ? f[0] : g[0];
        const int  o0  = base + c0 * 4608;
        #pragma unroll
        for (int c1 = 0; c1 < 2; ++c1) {
            const float w  = w0 * (c1 ? f[1] : g[1]);
            const __half* pc = R + (size_t)(o0 + c1 * 512) * 40;
            #pragma unroll
            for (int c = 0; c < 5; ++c) {
                HQ8 u; u.q = *(const uint4*)(pc + c * 8);
                float v000 = __half2float(u.h[0]);
                float v001 = __half2float(u.h[1]);
                float v010 = __half2float(u.h[2]);
                float v011 = __half2float(u.h[3]);
                float v100 = __half2float(u.h[4]);
                float v101 = __half2float(u.h[5]);
                float v110 = __half2float(u.h[6]);
                float v111 = __half2float(u.h[7]);
                float e00 = lerpf(v000, v001, f2);
                float e01 = lerpf(v010, v011, f2);
                float e10 = lerpf(v100, v101, f2);
                float e11 = lerpf(v110, v111, f2);
                float d0  = lerpf(e00, e01, f4);
                float d1  = lerpf(e10, e11, f4);
                float s   = lerpf(d0, d1, f3);
                if      (c == 0) acc0 = fmaf(w, s, acc0);
                else if (c == 1) acc1 = fmaf(w, s, acc1);
                else if (c == 2) acc2 = fmaf(w, s, acc2);
                else if (c == 3) acc3 = fmaf(w, s, acc3);
                else             acc4 = fmaf(w, s, acc4);
            }
        }
    }
    float* op = out + (size_t)b * 5 * HW_ + hw;
    __builtin_nontemporal_store(acc0, op + 0 * HW_);
    __builtin_nontemporal_store(acc1, op + 1 * HW_);
    __builtin_nontemporal_store(acc2, op + 2 * HW_);
    __builtin_nontemporal_store(acc3, op + 3 * HW_);
    __builtin_nontemporal_store(acc4, op + 4 * HW_);
}

extern "C" void kernel_launch(void* const* d_in, const int* in_sizes, int n_in,
                              void* d_out, int out_size, void* d_ws, size_t ws_size,
                              hipStream_t stream)
{
    const float* x   = (const float*)d_in[0];
    const float* lut = (const float*)d_in[1];
    float* out       = (float*)d_out;
    char* ws         = (char*)d_ws;

    if (ws != nullptr && ws_size >= WS_NEED) {
        __half* R      = (__half*)(ws + OFF_R);
        uint4*  pay    = (uint4*)(ws + OFF_PAY);
        uint*   sortp  = (uint*)(ws + OFF_POS);
        uint*   gcnt   = (uint*)(ws + OFF_CNT);

        hipMemsetAsync(gcnt, 0, CNT_BYTES, stream);
        k1_buildR   <<<648, 256, 0, stream>>>(lut, R);
        k4_fused    <<<NPIX / PXB, 1024, 0, stream>>>(x, gcnt, pay, sortp);
        k5_compute  <<<4 * NBIN, 256, 0, stream>>>(R, gcnt, pay);
        k5_ovf      <<<64, 256, 0, stream>>>(x, R, gcnt, pay);
        k6_unpermute<<<NPIX / 4096, 1024, 0, stream>>>(sortp, pay, out);
    } else if (ws != nullptr && ws_size >= R_BYTES) {
        // note: buildR3 uses the round-3 corner layout; gather3 lerps match it
        __half* R = (__half*)ws;
        int nb = (5 * NCELL2 + 255) / 256;
        buildR3<<<nb, 256, 0, stream>>>(lut, R);
        gather3<<<NPIX / 256, 256, 0, stream>>>(x, R, out);
    }
}